// Round 1
// baseline (138.299 us; speedup 1.0000x reference)
//
#include <hip/hip_runtime.h>
#include <math.h>

#define ROWS 11

// ---------------- Layer 1: [11,8192] @ [8192,512] -> partials ----------------
// grid (8 col-tiles, 32 k-chunks of 256), block 256.
// Thread: one column, 64 k values. x[r][k] is wave-uniform -> s_load.
__global__ __launch_bounds__(256) void k_l1(const float* __restrict__ xn,
                                            const float* __restrict__ xe,
                                            const float* __restrict__ W1,
                                            float* __restrict__ p1) {
  __shared__ float red[4][ROWS][64];
  const int lane = threadIdx.x & 63;
  const int ksub = threadIdx.x >> 6;
  const int col  = blockIdx.x * 64 + lane;
  const int k0   = __builtin_amdgcn_readfirstlane((int)(blockIdx.y * 256 + ksub * 64));

  float acc[ROWS];
#pragma unroll
  for (int r = 0; r < ROWS; ++r) acc[r] = 0.0f;

  const float* w = W1 + (size_t)k0 * 512 + col;
#pragma unroll 4
  for (int i = 0; i < 64; ++i) {
    const float wv = w[(size_t)i * 512];
    const int k = k0 + i;
    acc[0] = fmaf(xn[k], wv, acc[0]);
#pragma unroll
    for (int r = 0; r < 10; ++r)
      acc[r + 1] = fmaf(xe[r * 8192 + k], wv, acc[r + 1]);
  }

#pragma unroll
  for (int r = 0; r < ROWS; ++r) red[ksub][r][lane] = acc[r];
  __syncthreads();
  if (threadIdx.x < 64) {
#pragma unroll
    for (int r = 0; r < ROWS; ++r) {
      const float s = red[0][r][lane] + red[1][r][lane] +
                      red[2][r][lane] + red[3][r][lane];
      p1[((size_t)blockIdx.y * ROWS + r) * 512 + col] = s;
    }
  }
}

// ------------- Reduce 32 k-chunk partials, +b1, ReLU -> H1 [11,512] ----------
__global__ __launch_bounds__(256) void k_red1(const float* __restrict__ p1,
                                              const float* __restrict__ b1,
                                              float* __restrict__ H1) {
  const int idx = blockIdx.x * 256 + threadIdx.x;  // 0..5631
  if (idx < ROWS * 512) {
    const int col = idx % 512;
    float s = b1[col];
#pragma unroll 8
    for (int c = 0; c < 32; ++c) s += p1[(size_t)c * (ROWS * 512) + idx];
    H1[idx] = fmaxf(s, 0.0f);
  }
}

// ---------------- Layer 2: H1 [11,512] @ [512,256] -> partials ---------------
// grid (4 col-tiles, 4 k-chunks of 128), block 256. H1 via uniform s_load.
__global__ __launch_bounds__(256) void k_l2(const float* __restrict__ H1,
                                            const float* __restrict__ W2,
                                            float* __restrict__ p2) {
  __shared__ float red[4][ROWS][64];
  const int lane = threadIdx.x & 63;
  const int ksub = threadIdx.x >> 6;
  const int col  = blockIdx.x * 64 + lane;
  const int k0   = __builtin_amdgcn_readfirstlane((int)(blockIdx.y * 128 + ksub * 32));

  float acc[ROWS];
#pragma unroll
  for (int r = 0; r < ROWS; ++r) acc[r] = 0.0f;

#pragma unroll 4
  for (int i = 0; i < 32; ++i) {
    const int k = k0 + i;
    const float wv = W2[(size_t)k * 256 + col];
#pragma unroll
    for (int r = 0; r < ROWS; ++r)
      acc[r] = fmaf(H1[r * 512 + k], wv, acc[r]);
  }

#pragma unroll
  for (int r = 0; r < ROWS; ++r) red[ksub][r][lane] = acc[r];
  __syncthreads();
  if (threadIdx.x < 64) {
#pragma unroll
    for (int r = 0; r < ROWS; ++r) {
      const float s = red[0][r][lane] + red[1][r][lane] +
                      red[2][r][lane] + red[3][r][lane];
      p2[((size_t)blockIdx.y * ROWS + r) * 256 + col] = s;
    }
  }
}

// ------- Layer 3: reduce p2 (+b2, ReLU) staged in LDS, @ [256,128] -----------
// grid (2 col-tiles, 4 k-chunks of 64), block 256.
__global__ __launch_bounds__(256) void k_l3(const float* __restrict__ p2,
                                            const float* __restrict__ b2,
                                            const float* __restrict__ W3,
                                            float* __restrict__ p3) {
  __shared__ float H2s[ROWS * 64];  // this block's k-slice of relu(H2+b2)
  __shared__ float red[4][ROWS][64];
  const int lane = threadIdx.x & 63;
  const int ksub = threadIdx.x >> 6;
  const int col  = blockIdx.x * 64 + lane;

  // cooperative reduce of the 4 layer-2 k-chunk partials for our 64 k's
  for (int idx = threadIdx.x; idx < ROWS * 64; idx += 256) {
    const int r = idx >> 6;
    const int kk = idx & 63;
    const int k = blockIdx.y * 64 + kk;
    float s = b2[k];
#pragma unroll
    for (int c = 0; c < 4; ++c) s += p2[((size_t)c * ROWS + r) * 256 + k];
    H2s[idx] = fmaxf(s, 0.0f);
  }
  __syncthreads();

  float acc[ROWS];
#pragma unroll
  for (int r = 0; r < ROWS; ++r) acc[r] = 0.0f;

#pragma unroll 4
  for (int i = 0; i < 16; ++i) {
    const int kk = ksub * 16 + i;                 // 0..63 within block slice
    const int k  = blockIdx.y * 64 + kk;
    const float wv = W3[(size_t)k * 128 + col];
#pragma unroll
    for (int r = 0; r < ROWS; ++r)
      acc[r] = fmaf(H2s[r * 64 + kk], wv, acc[r]);
  }

#pragma unroll
  for (int r = 0; r < ROWS; ++r) red[ksub][r][lane] = acc[r];
  __syncthreads();
  if (threadIdx.x < 64) {
#pragma unroll
    for (int r = 0; r < ROWS; ++r) {
      const float s = red[0][r][lane] + red[1][r][lane] +
                      red[2][r][lane] + red[3][r][lane];
      p3[((size_t)blockIdx.y * ROWS + r) * 128 + col] = s;
    }
  }
}

// ---------------- Finale: similarity math + integrator MLP -------------------
// single wave (64 threads); thread t owns enc columns {t, t+64}.
__device__ __forceinline__ float wredsum(float v) {
#pragma unroll
  for (int o = 32; o > 0; o >>= 1) v += __shfl_down(v, o, 64);
  return v;  // valid in lane 0
}

__global__ __launch_bounds__(64) void k_final(const float* __restrict__ p3,
                                              const float* __restrict__ b3,
                                              const float* __restrict__ mm,
                                              const float* __restrict__ Wi1,
                                              const float* __restrict__ bi1,
                                              const float* __restrict__ Wi2,
                                              const float* __restrict__ bi2,
                                              const float* __restrict__ Wi3,
                                              const float* __restrict__ bi3,
                                              float* __restrict__ out) {
  __shared__ float comb[134];
  __shared__ float h1s[64];
  const int t = threadIdx.x;

  // new_enc (row 0): reduce 4 k-chunk partials + b3
  float n0 = b3[t], n1 = b3[t + 64];
#pragma unroll
  for (int s = 0; s < 4; ++s) {
    n0 += p3[((size_t)s * ROWS + 0) * 128 + t];
    n1 += p3[((size_t)s * ROWS + 0) * 128 + t + 64];
  }
  comb[t] = n0;
  comb[t + 64] = n1;
  if (t < 6) comb[128 + t] = mm[t];

  const float nn = wredsum(n0 * n0 + n1 * n1);  // lane 0

  float consist = 0.0f;  // lane 0 accumulates sum(geo - cos)
  for (int r = 1; r <= 10; ++r) {
    float e0 = b3[t], e1 = b3[t + 64];
#pragma unroll
    for (int s = 0; s < 4; ++s) {
      e0 += p3[((size_t)s * ROWS + r) * 128 + t];
      e1 += p3[((size_t)s * ROWS + r) * 128 + t + 64];
    }
    const float d0 = e0 - n0, d1 = e1 - n1;
    const float g = wredsum(d0 * d0 + d1 * d1);
    const float q = wredsum(e0 * e0 + e1 * e1);
    const float dd = wredsum(e0 * n0 + e1 * n1);
    if (t == 0) {
      const float geo = sqrtf(g);
      const float den = fmaxf(sqrtf(nn), 1e-8f) * fmaxf(sqrtf(q), 1e-8f);
      consist += geo - dd / den;
    }
  }

  __syncthreads();  // comb[] ready

  // integrator layer 1: [134] -> 64, ReLU
  float h = bi1[t];
  for (int k = 0; k < 134; ++k) h = fmaf(comb[k], Wi1[k * 64 + t], h);
  h1s[t] = fmaxf(h, 0.0f);
  __syncthreads();

  // layer 2: 64 -> 32 ReLU, then dot with Wi3 [32,1]
  float part = 0.0f;
  if (t < 32) {
    float h2 = bi2[t];
#pragma unroll 8
    for (int k = 0; k < 64; ++k) h2 = fmaf(h1s[k], Wi2[k * 32 + t], h2);
    part = fmaxf(h2, 0.0f) * Wi3[t];
  }
  const float qual = wredsum(part);
  if (t == 0) out[0] = consist * 0.1f + expf(-(qual + bi3[0]));
}

extern "C" void kernel_launch(void* const* d_in, const int* in_sizes, int n_in,
                              void* d_out, int out_size, void* d_ws, size_t ws_size,
                              hipStream_t stream) {
  (void)in_sizes; (void)n_in; (void)out_size; (void)ws_size;
  const float* xn  = (const float*)d_in[0];
  const float* xe  = (const float*)d_in[1];
  const float* mm  = (const float*)d_in[2];
  const float* W1  = (const float*)d_in[3];
  const float* b1  = (const float*)d_in[4];
  const float* W2  = (const float*)d_in[5];
  const float* b2  = (const float*)d_in[6];
  const float* W3  = (const float*)d_in[7];
  const float* b3  = (const float*)d_in[8];
  const float* Wi1 = (const float*)d_in[9];
  const float* bi1 = (const float*)d_in[10];
  const float* Wi2 = (const float*)d_in[11];
  const float* bi2 = (const float*)d_in[12];
  const float* Wi3 = (const float*)d_in[13];
  const float* bi3 = (const float*)d_in[14];
  float* out = (float*)d_out;

  char* ws = (char*)d_ws;
  float* p1 = (float*)(ws);             // 32*11*512*4 = 720896 B
  float* H1 = (float*)(ws + 720896);    // 11*512*4    =  22528 B
  float* p2 = (float*)(ws + 743424);    // 4*11*256*4  =  45056 B
  float* p3 = (float*)(ws + 788480);    // 4*11*128*4  =  22528 B

  hipLaunchKernelGGL(k_l1,   dim3(8, 32), dim3(256), 0, stream, xn, xe, W1, p1);
  hipLaunchKernelGGL(k_red1, dim3(22),    dim3(256), 0, stream, p1, b1, H1);
  hipLaunchKernelGGL(k_l2,   dim3(4, 4),  dim3(256), 0, stream, H1, W2, p2);
  hipLaunchKernelGGL(k_l3,   dim3(2, 4),  dim3(256), 0, stream, p2, b2, W3, p3);
  hipLaunchKernelGGL(k_final, dim3(1),    dim3(64),  0, stream,
                     p3, b3, mm, Wi1, bi1, Wi2, bi2, Wi3, bi3, out);
}

// Round 2
// 132.174 us; speedup vs baseline: 1.0463x; 1.0463x over previous
//
#include <hip/hip_runtime.h>
#include <math.h>

#define EPS 1e-8f

// ------------------------- grid barrier (64 blocks) --------------------------
__device__ __forceinline__ void gridbar(int* bar, int target) {
  __syncthreads();
  if (threadIdx.x == 0) {
    __threadfence();  // agent-scope release: flush L2 writebacks (multi-XCD)
    __hip_atomic_fetch_add(bar, 1, __ATOMIC_RELAXED, __HIP_MEMORY_SCOPE_AGENT);
    while (__hip_atomic_load(bar, __ATOMIC_RELAXED, __HIP_MEMORY_SCOPE_AGENT) < target) {
      __builtin_amdgcn_s_sleep(1);
    }
    __threadfence();  // acquire: invalidate stale cache lines
  }
  __syncthreads();
}

__device__ __forceinline__ float wredsum(float v) {
#pragma unroll
  for (int o = 32; o > 0; o >>= 1) v += __shfl_down(v, o, 64);
  return v;  // valid in lane 0
}

// ---------------- Layer 1: [11,8192] @ [8192,512] -> 32 k-chunk partials -----
// grid (8 col-tiles of 64, 32 k-chunks of 256), block 256 = 16 colgrp x 16 ksub.
// Thread: 4 cols (float4 W1 loads), 16 k. unroll 8 -> 8 KB/wave in flight.
__global__ __launch_bounds__(256) void k_l1(const float* __restrict__ xn,
                                            const float* __restrict__ xe,
                                            const float* __restrict__ W1,
                                            float* __restrict__ p1,
                                            int* __restrict__ bars) {
  if (blockIdx.x == 0 && blockIdx.y == 0 && threadIdx.x == 0) {
    bars[0] = 0; bars[1] = 0; bars[2] = 0;  // visible to k_rest after kernel boundary
  }
  __shared__ float red[11 * 16 * 65];  // 45760 B, stride 65 -> 2-way max (free)
  const int cg  = threadIdx.x & 15;
  const int ks  = threadIdx.x >> 4;
  const int col = blockIdx.x * 64 + cg * 4;
  const int k0  = blockIdx.y * 256 + ks * 16;

  float4 acc[11];
#pragma unroll
  for (int r = 0; r < 11; ++r) acc[r] = make_float4(0.f, 0.f, 0.f, 0.f);

#pragma unroll 8
  for (int i = 0; i < 16; ++i) {
    const int k = k0 + i;
    const float4 w = *(const float4*)&W1[(size_t)k * 512 + col];
    float xv = xn[k];
    acc[0].x = fmaf(xv, w.x, acc[0].x); acc[0].y = fmaf(xv, w.y, acc[0].y);
    acc[0].z = fmaf(xv, w.z, acc[0].z); acc[0].w = fmaf(xv, w.w, acc[0].w);
#pragma unroll
    for (int r = 0; r < 10; ++r) {
      const float xr = xe[r * 8192 + k];
      acc[r + 1].x = fmaf(xr, w.x, acc[r + 1].x);
      acc[r + 1].y = fmaf(xr, w.y, acc[r + 1].y);
      acc[r + 1].z = fmaf(xr, w.z, acc[r + 1].z);
      acc[r + 1].w = fmaf(xr, w.w, acc[r + 1].w);
    }
  }

#pragma unroll
  for (int r = 0; r < 11; ++r) {
    const int base = (r * 16 + ks) * 65 + cg * 4;
    red[base]     = acc[r].x; red[base + 1] = acc[r].y;
    red[base + 2] = acc[r].z; red[base + 3] = acc[r].w;
  }
  __syncthreads();
  if (threadIdx.x < 176) {
    const int r = threadIdx.x >> 4;
    const int c = threadIdx.x & 15;
    float4 s = make_float4(0.f, 0.f, 0.f, 0.f);
#pragma unroll
    for (int k = 0; k < 16; ++k) {
      const int b = (r * 16 + k) * 65 + c * 4;
      s.x += red[b]; s.y += red[b + 1]; s.z += red[b + 2]; s.w += red[b + 3];
    }
    *(float4*)&p1[((size_t)blockIdx.y * 11 + r) * 512 + blockIdx.x * 64 + c * 4] = s;
  }
}

// --------- Fused: reduce->H1 | L2 | L3 | similarity + integrator MLP ---------
// grid 64 blocks x 256 (all co-resident), 3 device-scope barriers.
__global__ __launch_bounds__(256) void k_rest(
    const float* __restrict__ p1, const float* __restrict__ b1,
    const float* __restrict__ W2, const float* __restrict__ b2,
    const float* __restrict__ W3, const float* __restrict__ b3,
    const float* __restrict__ mm,
    const float* __restrict__ Wi1, const float* __restrict__ bi1,
    const float* __restrict__ Wi2, const float* __restrict__ bi2,
    const float* __restrict__ Wi3, const float* __restrict__ bi3,
    float* __restrict__ H1, float* __restrict__ H2a, float* __restrict__ enca,
    int* __restrict__ bars, float* __restrict__ out) {
  __shared__ float red2[11 * 16 * 17];              // 11968 B
  __shared__ float red3[11 * 64 * 5];               // 14080 B
  __shared__ __align__(16) float wi1s[134 * 64];    // 34304 B
  __shared__ float comb[134];
  __shared__ float h1s[64];
  const int tid = threadIdx.x;
  const int b = blockIdx.x;

  // ---- Phase B1: H1 = relu(b1 + sum_ch p1); zero the atomic accumulators ----
  if (tid < 88) {
    const int idx = b * 88 + tid;   // covers 11*512 = 5632
    const int c = idx & 511;
    float s = b1[c];
#pragma unroll 8
    for (int ch = 0; ch < 32; ++ch) s += p1[(size_t)ch * 5632 + idx];
    H1[idx] = fmaxf(s, 0.f);
  } else if (tid < 132) {
    H2a[b * 44 + (tid - 88)] = 0.f;      // 64*44 = 2816
  } else if (tid < 154) {
    enca[b * 22 + (tid - 132)] = 0.f;    // 64*22 = 1408
  }
  gridbar(&bars[0], 64);

  // ---- Phase B2: H2a += H1 @ W2 (k-split over 4 block groups) ---------------
  {
    const int ct = b & 15, kt = b >> 4;          // 16 col-tiles x 4 k-tiles
    const int c = tid & 15, ksl = tid >> 4;      // 16 cols x 16 k-subs
    const int col = ct * 16 + c;
    float acc[11];
#pragma unroll
    for (int r = 0; r < 11; ++r) acc[r] = 0.f;
#pragma unroll
    for (int kk = 0; kk < 8; ++kk) {
      const int k = kt * 128 + kk * 16 + ksl;
      const float wv = W2[(size_t)k * 256 + col];
#pragma unroll
      for (int r = 0; r < 11; ++r) acc[r] = fmaf(H1[r * 512 + k], wv, acc[r]);
    }
#pragma unroll
    for (int r = 0; r < 11; ++r) red2[(r * 16 + ksl) * 17 + c] = acc[r];
  }
  __syncthreads();
  if (tid < 176) {
    const int r = tid >> 4, c = tid & 15;
    float s = 0.f;
#pragma unroll
    for (int ks = 0; ks < 16; ++ks) s += red2[(r * 16 + ks) * 17 + c];
    atomicAdd(&H2a[r * 256 + (b & 15) * 16 + c], s);
  }
  gridbar(&bars[1], 64);

  // ---- Phase C: enca += relu(H2a + b2) @ W3 (k-split over 2 block groups) ---
  {
    const int ct = b & 31, kt = b >> 5;          // 32 col-tiles x 2 k-tiles
    const int c = tid & 3, ksl = tid >> 2;       // 4 cols x 64 k-subs
    const int col = ct * 4 + c;
    float acc[11];
#pragma unroll
    for (int r = 0; r < 11; ++r) acc[r] = 0.f;
#pragma unroll
    for (int kk = 0; kk < 2; ++kk) {
      const int k = kt * 128 + kk * 64 + ksl;
      const float wv = W3[(size_t)k * 128 + col];
      const float bb = b2[k];
#pragma unroll
      for (int r = 0; r < 11; ++r) {
        const float h2 = fmaxf(H2a[r * 256 + k] + bb, 0.f);
        acc[r] = fmaf(h2, wv, acc[r]);
      }
    }
#pragma unroll
    for (int r = 0; r < 11; ++r) red3[(r * 64 + ksl) * 5 + c] = acc[r];
  }
  __syncthreads();
  if (tid < 44) {
    const int r = tid >> 2, c = tid & 3;
    float s = 0.f;
#pragma unroll 8
    for (int ks = 0; ks < 64; ++ks) s += red3[(r * 64 + ks) * 5 + c];
    atomicAdd(&enca[r * 128 + (b & 31) * 4 + c], s);
  }
  gridbar(&bars[2], 64);
  if (b != 0) return;

  // ---- Phase D (block 0): similarity + integrator -------------------------
  for (int i = tid; i < (134 * 64) / 4; i += 256)   // prefetch Wi1 -> LDS
    *(float4*)&wi1s[i * 4] = *(const float4*)&Wi1[i * 4];

  const int t = tid;
  float n0 = 0.f, n1 = 0.f, consist = 0.f, nn = 0.f;
  if (t < 64) {
    n0 = enca[t] + b3[t];
    n1 = enca[64 + t] + b3[64 + t];
    comb[t] = n0; comb[64 + t] = n1;
    if (t < 6) comb[128 + t] = mm[t];
    nn = wredsum(n0 * n0 + n1 * n1);
#pragma unroll
    for (int r = 1; r <= 10; ++r) {
      const float e0 = enca[r * 128 + t] + b3[t];
      const float e1 = enca[r * 128 + 64 + t] + b3[64 + t];
      const float d0 = e0 - n0, d1 = e1 - n1;
      const float g  = wredsum(d0 * d0 + d1 * d1);
      const float q  = wredsum(e0 * e0 + e1 * e1);
      const float dd = wredsum(e0 * n0 + e1 * n1);
      if (t == 0) {
        const float geo = sqrtf(g);
        const float den = fmaxf(sqrtf(nn), EPS) * fmaxf(sqrtf(q), EPS);
        consist += geo - dd / den;
      }
    }
  }
  __syncthreads();  // comb + wi1s ready
  if (t < 64) {
    float h = bi1[t];
#pragma unroll 4
    for (int k = 0; k < 134; ++k) h = fmaf(comb[k], wi1s[k * 64 + t], h);
    h1s[t] = fmaxf(h, 0.f);
  }
  __syncthreads();
  if (t < 64) {
    float part = 0.f;
    if (t < 32) {
      float h2 = bi2[t];
#pragma unroll 8
      for (int k = 0; k < 64; ++k) h2 = fmaf(h1s[k], Wi2[k * 32 + t], h2);
      part = fmaxf(h2, 0.f) * Wi3[t];
    }
    const float qual = wredsum(part);
    if (t == 0) out[0] = consist * 0.1f + expf(-(qual + bi3[0]));
  }
}

extern "C" void kernel_launch(void* const* d_in, const int* in_sizes, int n_in,
                              void* d_out, int out_size, void* d_ws, size_t ws_size,
                              hipStream_t stream) {
  (void)in_sizes; (void)n_in; (void)out_size; (void)ws_size;
  const float* xn  = (const float*)d_in[0];
  const float* xe  = (const float*)d_in[1];
  const float* mm  = (const float*)d_in[2];
  const float* W1  = (const float*)d_in[3];
  const float* b1  = (const float*)d_in[4];
  const float* W2  = (const float*)d_in[5];
  const float* b2  = (const float*)d_in[6];
  const float* W3  = (const float*)d_in[7];
  const float* b3  = (const float*)d_in[8];
  const float* Wi1 = (const float*)d_in[9];
  const float* bi1 = (const float*)d_in[10];
  const float* Wi2 = (const float*)d_in[11];
  const float* bi2 = (const float*)d_in[12];
  const float* Wi3 = (const float*)d_in[13];
  const float* bi3 = (const float*)d_in[14];
  float* out = (float*)d_out;

  char* ws = (char*)d_ws;
  float* p1   = (float*)(ws);            // 32*11*512*4 = 720896 B
  float* H1   = (float*)(ws + 720896);   // 11*512*4    =  22528 B
  float* H2a  = (float*)(ws + 743424);   // 11*256*4    =  11264 B
  float* enca = (float*)(ws + 754688);   // 11*128*4    =   5632 B
  int*   bars = (int*)  (ws + 760320);   // 3*4 B

  hipLaunchKernelGGL(k_l1, dim3(8, 32), dim3(256), 0, stream, xn, xe, W1, p1, bars);
  hipLaunchKernelGGL(k_rest, dim3(64), dim3(256), 0, stream,
                     p1, b1, W2, b2, W3, b3, mm,
                     Wi1, bi1, Wi2, bi2, Wi3, bi3,
                     H1, H2a, enca, bars, out);
}